// Round 7
// baseline (334.660 us; speedup 1.0000x reference)
//
#include <hip/hip_runtime.h>

// Problem constants (match reference)
#define N_NODES 40000
#define ISIZE   64
#define KNN     24
#define NE      (N_NODES * KNN)      // 960000 edges (= E_ADJ as well)
#define OMEGA   0.9f
#define CAP     64                   // per-node bucket capacity (max deg ~46)
#define NBUCK   80                   // destination buckets of 512 nodes (c>>9)
#define LBUCK   10                   // buckets per XCD (NBUCK/8)
#define BCAP    16384                // edges per bucket capacity
#define EPT     8                    // edges per thread in k_bin
#define PBCH    512                  // edges per block in k_scatter2

// ---- bf16 helpers (storage-only precision; all math in fp32) -------------
__device__ __forceinline__ float bf2f(unsigned short s) {
    return __uint_as_float(((unsigned)s) << 16);
}
__device__ __forceinline__ unsigned short f2bf(float f) {  // round-nearest-even
    unsigned u = __float_as_uint(f);
    u += 0x7fffu + ((u >> 16) & 1u);
    return (unsigned short)(u >> 16);
}
__device__ __forceinline__ float bflo(unsigned u) { return __uint_as_float(u << 16); }
__device__ __forceinline__ float bfhi(unsigned u) { return __uint_as_float(u & 0xffff0000u); }
__device__ __forceinline__ float ldf(float x) { return x; }
__device__ __forceinline__ float ldf(unsigned short x) { return bf2f(x); }

// ---- pass 1: bin edges by destination range, packed (r<<16)|c ------------
__global__ void k_bin(const int* __restrict__ row, const int* __restrict__ col,
                      int* __restrict__ bcnt, unsigned* __restrict__ bbuf,
                      unsigned* __restrict__ ovf2, int* __restrict__ ovf2_cnt) {
    __shared__ int lcnt[NBUCK];
    __shared__ int lbase[NBUCK];
    int tid = threadIdx.x;
    for (int b = tid; b < NBUCK; b += 256) lcnt[b] = 0;
    __syncthreads();
    int e0 = blockIdx.x * (256 * EPT);
    int myslot[EPT]; int myb[EPT]; unsigned myp[EPT];
    for (int k = 0; k < EPT; k++) {
        int e = e0 + k * 256 + tid;
        if (e < NE) {
            int r = row[e], c = col[e];
            int b = c >> 9;
            myb[k] = b;
            myp[k] = ((unsigned)r << 16) | (unsigned)c;
            myslot[k] = atomicAdd(&lcnt[b], 1);
        } else myb[k] = -1;
    }
    __syncthreads();
    for (int b = tid; b < NBUCK; b += 256)
        lbase[b] = (lcnt[b] > 0) ? atomicAdd(&bcnt[b], lcnt[b]) : 0;
    __syncthreads();
    for (int k = 0; k < EPT; k++) {
        if (myb[k] < 0) continue;
        int pos = lbase[myb[k]] + myslot[k];
        if (pos < BCAP) bbuf[myb[k] * BCAP + pos] = myp[k];
        else { int p = atomicAdd(ovf2_cnt, 1); ovf2[p] = myp[k]; }
    }
}

// ---- pass 2: XCD-affine scatter into ebuf; cnt[] ends up as the degree ---
__global__ void k_scatter2(const unsigned* __restrict__ bbuf, const int* __restrict__ bcnt,
                           int* __restrict__ cnt, unsigned short* __restrict__ ebuf,
                           unsigned* __restrict__ ovf, int* __restrict__ ovf_cnt) {
    int xcd = blockIdx.x & 7;
    int t   = blockIdx.x >> 3;
    int lb  = t % LBUCK;
    int chunk = t / LBUCK;                 // 0..BCAP/PBCH-1
    int b = xcd + 8 * lb;                  // bucket; b%8==xcd for L2 locality
    int n = min(bcnt[b], BCAP);
    int start = chunk * PBCH;
    if (start >= n) return;
    int end = min(start + PBCH, n);
    for (int idx = start + threadIdx.x; idx < end; idx += 256) {
        unsigned p = bbuf[b * BCAP + idx];
        int c = (int)(p & 0xffffu), r = (int)(p >> 16);
        int slot = atomicAdd(&cnt[c], 1);
        if (slot < CAP) ebuf[c * CAP + slot] = (unsigned short)r;
        else { int q = atomicAdd(ovf_cnt, 1); ovf[q] = p; }
    }
}

// ---- bin-overflow fallback (normally 0 edges) ----------------------------
__global__ void k_scat_ovf(const unsigned* __restrict__ ovf2, const int* __restrict__ ovf2_cnt,
                           int* __restrict__ cnt, unsigned short* __restrict__ ebuf,
                           unsigned* __restrict__ ovf, int* __restrict__ ovf_cnt) {
    int m = ovf2_cnt[0];
    for (int t = blockIdx.x * 256 + threadIdx.x; t < m; t += gridDim.x * 256) {
        unsigned p = ovf2[t];
        int c = (int)(p & 0xffffu), r = (int)(p >> 16);
        int slot = atomicAdd(&cnt[c], 1);
        if (slot < CAP) ebuf[c * CAP + slot] = (unsigned short)r;
        else { int q = atomicAdd(ovf_cnt, 1); ovf[q] = p; }
    }
}

__global__ void k_dinv(const int* __restrict__ cnt, float* __restrict__ dinv) {
    int n = blockIdx.x * 256 + threadIdx.x;
    if (n < N_NODES) dinv[n] = rsqrtf(1.0f + (float)cnt[n]);
}

// ---- zero ovfacc entries for CAP-overflow destinations (normally empty) --
__global__ void k_zero_ovf(float* __restrict__ ovfacc,
                           const unsigned* __restrict__ ovf, const int* __restrict__ ovf_cnt) {
    int total = ovf_cnt[0] * 64;
    for (int t = blockIdx.x * 256 + threadIdx.x; t < total; t += gridDim.x * 256) {
        unsigned p = ovf[t >> 6];
        int c = (int)(p & 0xffffu);
        ovfacc[c * 64 + (t & 63)] = 0.0f;
    }
}

// ---- CAP-overflow fallback (normally 0): ovfacc[c] += dinv[r]*xw[r] ------
__global__ void k_ovf(const unsigned short* __restrict__ X0, const unsigned short* __restrict__ X1,
                      float* __restrict__ ovfacc, const float* __restrict__ dinv,
                      const unsigned* __restrict__ ovf, const int* __restrict__ ovf_cnt) {
    int total = ovf_cnt[0] * 64;
    for (int t = blockIdx.x * 256 + threadIdx.x; t < total; t += gridDim.x * 256) {
        unsigned p = ovf[t >> 6];
        int f = t & 63;
        int c = (int)(p & 0xffffu), r = (int)(p >> 16);
        float x = (f < 32) ? bf2f(X0[r * 32 + f]) : bf2f(X1[r * 32 + f - 32]);
        atomicAdd(&ovfacc[c * 64 + f], dinv[r] * x);
    }
}

// ---- Y = X @ W  (N x 64) * (64 x 64), bf16 split-half output -------------
template<typename T>
__global__ void k_gemm(const T* __restrict__ X, const float* __restrict__ W,
                       unsigned short* __restrict__ Y0, unsigned short* __restrict__ Y1) {
    __shared__ float sW[64 * 64];
    __shared__ float sX[32 * 64];
    int row0 = blockIdx.x * 32;
    for (int t = threadIdx.x; t < 64 * 64; t += 256) sW[t] = W[t];
    for (int t = threadIdx.x; t < 32 * 64; t += 256) sX[t] = ldf(X[row0 * 64 + t]);
    __syncthreads();
    int col = threadIdx.x & 63;
    int rl  = threadIdx.x >> 6;           // 0..3
    for (int r = rl; r < 32; r += 4) {
        float acc = 0.0f;
#pragma unroll
        for (int kk = 0; kk < 64; kk++) acc += sX[r * 64 + kk] * sW[kk * 64 + col];
        if (col < 32) Y0[(row0 + r) * 32 + col]      = f2bf(acc);
        else          Y1[(row0 + r) * 32 + col - 32] = f2bf(acc);
    }
}

// ---- pull aggregation, one wave per TWO nodes, phased half-gathers -------
template<bool RELU, bool NORM>
__global__ void k_aggf2(const unsigned short* __restrict__ X0, const unsigned short* __restrict__ X1,
                        unsigned short* __restrict__ outF,     // full rows (layer 1)
                        unsigned short* __restrict__ O0,       // split (layer 2)
                        unsigned short* __restrict__ O1,
                        const float* __restrict__ ovfacc,
                        const float* __restrict__ dinv, const int* __restrict__ cnt,
                        const unsigned short* __restrict__ ebuf, const float* __restrict__ bias) {
    int w = (blockIdx.x * 256 + threadIdx.x) >> 6;   // wave id, 2 nodes/wave
    int lane = threadIdx.x & 63;
    int half = lane >> 5, sl = lane & 31;
    int n = w * 2 + half;
    if (n >= N_NODES) return;                        // n uniform per 32-lane half
    int deg = cnt[n];
    int bucketed = min(deg, CAP);
    int nb0 = min(bucketed, 32);
    int nb1 = bucketed - nb0;

    int   r0v = 0, r1v = 0;
    float d0v = 0.0f, d1v = 0.0f;
    if (sl < nb0) { r0v = (int)ebuf[n * CAP + sl];      d0v = dinv[r0v]; }
    if (sl < nb1) { r1v = (int)ebuf[n * CAP + 32 + sl]; d1v = dinv[r1v]; }

    float acc0 = 0.0f, acc1 = 0.0f;
    if (deg > CAP) {                     // overflow path (never in practice)
        acc0 = ovfacc[n * 64 + sl];
        acc1 = ovfacc[n * 64 + 32 + sl];
    }

    // Phase A: features 0..31 from X0
    {
        int d = 0;
        for (; d + 3 < nb0; d += 4) {
            int   ra = __shfl(r0v, d, 32),     rb = __shfl(r0v, d + 1, 32);
            int   rc = __shfl(r0v, d + 2, 32), rd = __shfl(r0v, d + 3, 32);
            float ca = __shfl(d0v, d, 32),     cb = __shfl(d0v, d + 1, 32);
            float cc = __shfl(d0v, d + 2, 32), cd = __shfl(d0v, d + 3, 32);
            acc0 += ca * bf2f(X0[ra * 32 + sl]) + cb * bf2f(X0[rb * 32 + sl])
                  + cc * bf2f(X0[rc * 32 + sl]) + cd * bf2f(X0[rd * 32 + sl]);
        }
        for (; d < nb0; d++)
            acc0 += __shfl(d0v, d, 32) * bf2f(X0[__shfl(r0v, d, 32) * 32 + sl]);
        for (d = 0; d < nb1; d++)
            acc0 += __shfl(d1v, d, 32) * bf2f(X0[__shfl(r1v, d, 32) * 32 + sl]);
    }
    // Phase B: features 32..63 from X1
    {
        int d = 0;
        for (; d + 3 < nb0; d += 4) {
            int   ra = __shfl(r0v, d, 32),     rb = __shfl(r0v, d + 1, 32);
            int   rc = __shfl(r0v, d + 2, 32), rd = __shfl(r0v, d + 3, 32);
            float ca = __shfl(d0v, d, 32),     cb = __shfl(d0v, d + 1, 32);
            float cc = __shfl(d0v, d + 2, 32), cd = __shfl(d0v, d + 3, 32);
            acc1 += ca * bf2f(X1[ra * 32 + sl]) + cb * bf2f(X1[rb * 32 + sl])
                  + cc * bf2f(X1[rc * 32 + sl]) + cd * bf2f(X1[rd * 32 + sl]);
        }
        for (; d < nb0; d++)
            acc1 += __shfl(d0v, d, 32) * bf2f(X1[__shfl(r0v, d, 32) * 32 + sl]);
        for (d = 0; d < nb1; d++)
            acc1 += __shfl(d1v, d, 32) * bf2f(X1[__shfl(r1v, d, 32) * 32 + sl]);
    }

    float di = dinv[n];
    float v0 = di * acc0 + di * di * bf2f(X0[n * 32 + sl]) + bias[sl];
    float v1 = di * acc1 + di * di * bf2f(X1[n * 32 + sl]) + bias[32 + sl];
    if (RELU) { v0 = fmaxf(v0, 0.0f); v1 = fmaxf(v1, 0.0f); }
    if (NORM) {
        float s = v0 * v0 + v1 * v1;
#pragma unroll
        for (int m = 1; m < 32; m <<= 1) s += __shfl_xor(s, m, 32);
        float inv = 1.0f / fmaxf(sqrtf(s), 1e-12f);
        v0 *= inv; v1 *= inv;
        O0[n * 32 + sl] = f2bf(v0);
        O1[n * 32 + sl] = f2bf(v1);
    } else {
        outF[n * 64 + sl]      = f2bf(v0);
        outF[n * 64 + 32 + sl] = f2bf(v1);
    }
}

// ---- reverse-edge match: scan j's 24-edge slice; working set = j_idx only -
__global__ void k_rev(const int* __restrict__ j_idx, unsigned char* __restrict__ revb) {
    int t = blockIdx.x * 256 + threadIdx.x;   // NE*8 threads
    int e = t >> 3;
    int q = t & 7;
    int i = e / KNN;
    int j = j_idx[e];
    const int* jj = j_idx + j * KNN;
    int rt = 255;
    if (jj[q] == i) rt = q;
    if (jj[8 + q] == i) rt = min(rt, 8 + q);
    if (jj[16 + q] == i) rt = min(rt, 16 + q);
#pragma unroll
    for (int m = 1; m < 8; m <<= 1) rt = min(rt, __shfl_xor(rt, m));
    if (q == 0) revb[e] = (unsigned char)rt;
}

// ---- pass A: partial dot over feature half 0 (h0 = 2.56 MB, L2-resident) -
__global__ void k_dot0(const uint2* __restrict__ h0b, const int* __restrict__ j_idx,
                       float* __restrict__ pdot) {
    int t = blockIdx.x * 256 + threadIdx.x;   // NE*8 threads
    int e = t >> 3;
    int q = t & 7;
    int i = e / KNN;
    int j = j_idx[e];
    uint2 a = h0b[i * 8 + q];
    uint2 b = h0b[j * 8 + q];
    float s = bflo(a.x) * bflo(b.x) + bfhi(a.x) * bfhi(b.x)
            + bflo(a.y) * bflo(b.y) + bfhi(a.y) * bfhi(b.y);
    s += __shfl_xor(s, 1);
    s += __shfl_xor(s, 2);
    s += __shfl_xor(s, 4);
    if (q == 0) pdot[e] = s;
}

// ---- pass B: half 1 dot + finalize + symmetrize --------------------------
__global__ void k_edgesym2(const uint2* __restrict__ h1b, const float* __restrict__ pdot,
                           const float* __restrict__ s_d, const int* __restrict__ j_idx,
                           const unsigned char* __restrict__ revb,
                           float* __restrict__ outS,     // d_out + 2E, holds vals_s [2E]
                           float* __restrict__ deg2x) {  // 8 per-XCD copies
    int t = blockIdx.x * 256 + threadIdx.x;   // NE*8 threads
    int e = t >> 3;
    int q = t & 7;
    int i = e / KNN;
    int j = j_idx[e];
    uint2 a = h1b[i * 8 + q];
    uint2 b = h1b[j * 8 + q];
    float s = bflo(a.x) * bflo(b.x) + bfhi(a.x) * bfhi(b.x)
            + bflo(a.y) * bflo(b.y) + bfhi(a.y) * bfhi(b.y);
    s += __shfl_xor(s, 1);
    s += __shfl_xor(s, 2);
    s += __shfl_xor(s, 4);
    if (q == 0) {
        s += pdot[e];
        float base = OMEGA * fmaxf(s, 0.0f);
        int rt = revb[e];
        float v, v2;
        if (rt != 255) {                     // reverse edge exists (rare)
            int rev = j * KNN + rt;
            v  = base + 0.5f * (1.0f - OMEGA) * (s_d[e] + s_d[rev]);
            v2 = 0.0f;
        } else {
            v  = base + (1.0f - OMEGA) * s_d[e];
            v2 = v;
        }
        outS[e] = v;
        outS[NE + e] = v2;
        if (v2 != 0.0f) atomicAdd(&deg2x[(blockIdx.x & 7) * N_NODES + j], v2);
    }
}

// ---- dinv2: atomic-free out-edge segment sum + per-XCD in-edge copies ----
__global__ void k_dinv2(const float* __restrict__ outS, const float* __restrict__ deg2x,
                        float* __restrict__ dinv2) {
    int n = blockIdx.x * 256 + threadIdx.x;
    if (n >= N_NODES) return;
    float d = 0.0f;
#pragma unroll
    for (int x = 0; x < 8; x++) d += deg2x[x * N_NODES + n];
    const float* p = outS + n * KNN;
#pragma unroll
    for (int q = 0; q < KNN; q++) d += p[q];
    dinv2[n] = (d > 0.0f) ? rsqrtf(fmaxf(d, 1e-12f)) : 0.0f;
}

// ---- final normalization: vals_norm = dinv2[r] * vals_s * dinv2[c] -------
__global__ void k_norm(const float* __restrict__ outS, const float* __restrict__ dinv2,
                       const int* __restrict__ j_idx, float* __restrict__ out) {
    int t = blockIdx.x * 256 + threadIdx.x;   // 2*NE threads
    int r, c;
    if (t < NE) { r = t / KNN; c = j_idx[t]; }
    else        { int e = t - NE; r = j_idx[e]; c = e / KNN; }
    out[t] = dinv2[r] * outS[t] * dinv2[c];
}

extern "C" void kernel_launch(void* const* d_in, const int* in_sizes, int n_in,
                              void* d_out, int out_size, void* d_ws, size_t ws_size,
                              hipStream_t stream) {
    const float* features = (const float*)d_in[0];
    const float* W1       = (const float*)d_in[1];
    const float* b1       = (const float*)d_in[2];
    const float* W2       = (const float*)d_in[3];
    const float* b2       = (const float*)d_in[4];
    const float* s_d      = (const float*)d_in[5];
    const int*   adj_row  = (const int*)d_in[6];
    const int*   adj_col  = (const int*)d_in[7];
    const int*   j_idx    = (const int*)d_in[9];
    float* out = (float*)d_out;

    const int N64 = N_NODES * 64;
    const int N32 = N_NODES * 32;
    // Workspace layout (4-byte words):
    // zero region: [deg2x 8N][cnt N][ovfcnts 16][bcnt NBUCK]
    // then: [dinv N][dinv2 N][A0 N32 us][A1 N32 us][B16 N64 us][H0 N32 us][H1 N32 us]
    //       [ebuf N*CAP us][OVFACC N64 f][ovf NE u][revb NE uchar]
    //       [bbuf NBUCK*BCAP u][pdot NE f (aliases ovf2)]
    float* ws = (float*)d_ws;
    float* deg2x   = ws;
    int*   cnt     = (int*)(deg2x + 8 * N_NODES);
    int*   ovfcnts = cnt + N_NODES;          // [0]=CAP ovf, [8]=bin ovf
    int*   bcnt    = ovfcnts + 16;
    float* dinv    = (float*)(bcnt + NBUCK);
    float* dinv2   = dinv + N_NODES;
    unsigned short* A0  = (unsigned short*)(dinv2 + N_NODES);
    unsigned short* A1  = A0 + N32;
    unsigned short* B16 = A1 + N32;
    unsigned short* H0  = B16 + N64;
    unsigned short* H1  = H0 + N32;
    unsigned short* ebuf = H1 + N32;         // N*CAP ushorts
    float*    OVFACC = (float*)(ebuf + N_NODES * CAP);
    unsigned* ovf  = (unsigned*)(OVFACC + N64);
    unsigned char* revb = (unsigned char*)(ovf + NE);
    unsigned* bbuf = (unsigned*)(revb + NE);
    float*    pdot = (float*)(bbuf + NBUCK * BCAP);
    unsigned* ovf2 = (unsigned*)pdot;        // alias: ovf2 dies before pdot is born

    // Re-init (ws is poisoned 0xAA before every call)
    size_t zero_bytes = (size_t)(8 * N_NODES + N_NODES + 16 + NBUCK) * 4;
    hipMemsetAsync(deg2x, 0, zero_bytes, stream);

    // Two-pass binned scatter (produces ebuf buckets + cnt degrees)
    k_bin<<<(NE + 256 * EPT - 1) / (256 * EPT), 256, 0, stream>>>(adj_row, adj_col, bcnt, bbuf, ovf2, ovfcnts + 8);
    k_scatter2<<<8 * LBUCK * (BCAP / PBCH), 256, 0, stream>>>(bbuf, bcnt, cnt, ebuf, ovf, ovfcnts);
    k_scat_ovf<<<8, 256, 0, stream>>>(ovf2, ovfcnts + 8, cnt, ebuf, ovf, ovfcnts);
    k_dinv<<<(N_NODES + 255) / 256, 256, 0, stream>>>(cnt, dinv);

    // Reverse-edge match (depends only on j_idx)
    k_rev<<<NE * 8 / 256, 256, 0, stream>>>(j_idx, revb);

    // Layer 1: (A0|A1) = X@W1 ; B16 = relu(agg + self + b1)
    k_gemm<float><<<N_NODES / 32, 256, 0, stream>>>(features, W1, A0, A1);
    k_zero_ovf<<<8, 256, 0, stream>>>(OVFACC, ovf, ovfcnts);
    k_ovf<<<16, 256, 0, stream>>>(A0, A1, OVFACC, dinv, ovf, ovfcnts);
    k_aggf2<true, false><<<(N_NODES / 2 * 64 + 255) / 256, 256, 0, stream>>>(A0, A1, B16, nullptr, nullptr, OVFACC, dinv, cnt, ebuf, b1);

    // Layer 2: (A0|A1) = B16@W2 ; (H0|H1) = normalize(agg + self + b2)
    k_gemm<unsigned short><<<N_NODES / 32, 256, 0, stream>>>(B16, W2, A0, A1);
    k_zero_ovf<<<8, 256, 0, stream>>>(OVFACC, ovf, ovfcnts);
    k_ovf<<<16, 256, 0, stream>>>(A0, A1, OVFACC, dinv, ovf, ovfcnts);
    k_aggf2<false, true><<<(N_NODES / 2 * 64 + 255) / 256, 256, 0, stream>>>(A0, A1, nullptr, H0, H1, OVFACC, dinv, cnt, ebuf, b2);

    // Edge scores: half-0 partial dots, then half-1 + symmetrize
    float* outS = out + 2 * NE;
    k_dot0<<<NE * 8 / 256, 256, 0, stream>>>((const uint2*)H0, j_idx, pdot);
    k_edgesym2<<<NE * 8 / 256, 256, 0, stream>>>((const uint2*)H1, pdot, s_d, j_idx, revb, outS, deg2x);
    k_dinv2<<<(N_NODES + 255) / 256, 256, 0, stream>>>(outS, deg2x, dinv2);

    // Final: vals_norm = out[0..2E)
    k_norm<<<2 * NE / 256, 256, 0, stream>>>(outS, dinv2, j_idx, out);
}

// Round 8
// 325.516 us; speedup vs baseline: 1.0281x; 1.0281x over previous
//
#include <hip/hip_runtime.h>

// Problem constants (match reference)
#define N_NODES 40000
#define ISIZE   64
#define KNN     24
#define NE      (N_NODES * KNN)      // 960000 edges (= E_ADJ as well)
#define OMEGA   0.9f
#define CAP     64                   // per-node bucket capacity (max deg ~46)
#define NBUCK   80                   // buckets of 512 nodes (idx>>9)
#define LBUCK   10                   // buckets per XCD (NBUCK/8)
#define BCAP    16384                // adj edges per bucket capacity (mean 12288)
#define JBCAP   16384                // learner edges per bucket capacity
#define EPT     8                    // edges per thread in k_bin
#define PBCH    512                  // edges per block in k_scatter2

// ---- bf16 helpers (storage-only precision; all math in fp32) -------------
__device__ __forceinline__ float bf2f(unsigned short s) {
    return __uint_as_float(((unsigned)s) << 16);
}
__device__ __forceinline__ unsigned short f2bf(float f) {  // round-nearest-even
    unsigned u = __float_as_uint(f);
    u += 0x7fffu + ((u >> 16) & 1u);
    return (unsigned short)(u >> 16);
}
__device__ __forceinline__ float bflo(unsigned u) { return __uint_as_float(u << 16); }
__device__ __forceinline__ float bfhi(unsigned u) { return __uint_as_float(u & 0xffff0000u); }
__device__ __forceinline__ float ldf(float x) { return x; }
__device__ __forceinline__ float ldf(unsigned short x) { return bf2f(x); }

// ---- bin BOTH edge sets: adj by col (pack r<<16|c), learner by j (pack (j&511)<<20|e)
__global__ void k_bin(const int* __restrict__ row, const int* __restrict__ col,
                      const int* __restrict__ j_idx,
                      int* __restrict__ bcnt, unsigned* __restrict__ bbuf,
                      unsigned* __restrict__ ovf2, int* __restrict__ ovf2_cnt,
                      int* __restrict__ jbcnt, unsigned* __restrict__ jbbuf,
                      unsigned* __restrict__ jovf, int* __restrict__ jovf_cnt) {
    __shared__ int lcnt[NBUCK];
    __shared__ int lbase[NBUCK];
    const int NB_ADJ = (NE + 256 * EPT - 1) / (256 * EPT);
    int tid = threadIdx.x;
    bool adj = (int)blockIdx.x < NB_ADJ;
    int blk = adj ? blockIdx.x : blockIdx.x - NB_ADJ;
    for (int b = tid; b < NBUCK; b += 256) lcnt[b] = 0;
    __syncthreads();
    int e0 = blk * (256 * EPT);
    int myslot[EPT]; int myb[EPT]; unsigned myp[EPT];
    for (int k = 0; k < EPT; k++) {
        int e = e0 + k * 256 + tid;
        if (e < NE) {
            int b; unsigned p;
            if (adj) { int r = row[e], c = col[e]; b = c >> 9; p = ((unsigned)r << 16) | (unsigned)c; }
            else     { int j = j_idx[e];           b = j >> 9; p = ((unsigned)(j & 511) << 20) | (unsigned)e; }
            myb[k] = b; myp[k] = p;
            myslot[k] = atomicAdd(&lcnt[b], 1);
        } else myb[k] = -1;
    }
    __syncthreads();
    int* gcnt = adj ? bcnt : jbcnt;
    for (int b = tid; b < NBUCK; b += 256)
        lbase[b] = (lcnt[b] > 0) ? atomicAdd(&gcnt[b], lcnt[b]) : 0;
    __syncthreads();
    unsigned* gbuf = adj ? bbuf : jbbuf;
    unsigned* govf = adj ? ovf2 : jovf;
    int* gocnt = adj ? ovf2_cnt : jovf_cnt;
    int capb = adj ? BCAP : JBCAP;
    for (int k = 0; k < EPT; k++) {
        if (myb[k] < 0) continue;
        int pos = lbase[myb[k]] + myslot[k];
        if (pos < capb) gbuf[myb[k] * capb + pos] = myp[k];
        else { int p = atomicAdd(gocnt, 1); govf[p] = myp[k]; }
    }
}

// ---- XCD-affine scatter into ebuf (+ adj-bin-overflow tail blocks) -------
__global__ void k_scatter2(const unsigned* __restrict__ bbuf, const int* __restrict__ bcnt,
                           int* __restrict__ cnt, unsigned short* __restrict__ ebuf,
                           unsigned* __restrict__ ovf, int* __restrict__ ovf_cnt,
                           const unsigned* __restrict__ ovf2, const int* __restrict__ ovf2_cnt) {
    const int MAIN = 8 * LBUCK * (BCAP / PBCH);   // 2560
    if ((int)blockIdx.x >= MAIN) {                // adj bin-overflow fallback (normally 0)
        int m = ovf2_cnt[0];
        for (int t = (blockIdx.x - MAIN) * 256 + threadIdx.x; t < m; t += 8 * 256) {
            unsigned p = ovf2[t];
            int c = (int)(p & 0xffffu), r = (int)(p >> 16);
            int slot = atomicAdd(&cnt[c], 1);
            if (slot < CAP) ebuf[c * CAP + slot] = (unsigned short)r;
            else { int q = atomicAdd(ovf_cnt, 1); ovf[q] = p; }
        }
        return;
    }
    int xcd = blockIdx.x & 7;
    int t   = blockIdx.x >> 3;
    int lb  = t % LBUCK;
    int chunk = t / LBUCK;
    int b = xcd + 8 * lb;                  // bucket; b%8==xcd for L2 locality
    int n = min(bcnt[b], BCAP);
    int start = chunk * PBCH;
    if (start >= n) return;
    int end = min(start + PBCH, n);
    for (int idx = start + threadIdx.x; idx < end; idx += 256) {
        unsigned p = bbuf[b * BCAP + idx];
        int c = (int)(p & 0xffffu), r = (int)(p >> 16);
        int slot = atomicAdd(&cnt[c], 1);
        if (slot < CAP) ebuf[c * CAP + slot] = (unsigned short)r;
        else { int q = atomicAdd(ovf_cnt, 1); ovf[q] = p; }
    }
}

// ---- fused: gemm layer1 (blocks<GB) | dinv (GB..GB+DB) | rev scan (rest) -
__global__ void k_fused1(const float* __restrict__ X, const float* __restrict__ W,
                         unsigned short* __restrict__ Y0, unsigned short* __restrict__ Y1,
                         const int* __restrict__ cnt, float* __restrict__ dinv,
                         const int* __restrict__ j_idx, unsigned char* __restrict__ revb) {
    __shared__ float sW[64 * 64];
    __shared__ float sX[32 * 64];
    const int GB = N_NODES / 32;            // 1250
    const int DB = (N_NODES + 255) / 256;   // 157
    int bx = blockIdx.x;
    if (bx < GB) {
        int row0 = bx * 32;
        for (int t = threadIdx.x; t < 64 * 64; t += 256) sW[t] = W[t];
        for (int t = threadIdx.x; t < 32 * 64; t += 256) sX[t] = X[row0 * 64 + t];
        __syncthreads();
        int col = threadIdx.x & 63;
        int rl  = threadIdx.x >> 6;
        for (int r = rl; r < 32; r += 4) {
            float acc = 0.0f;
#pragma unroll
            for (int kk = 0; kk < 64; kk++) acc += sX[r * 64 + kk] * sW[kk * 64 + col];
            if (col < 32) Y0[(row0 + r) * 32 + col]      = f2bf(acc);
            else          Y1[(row0 + r) * 32 + col - 32] = f2bf(acc);
        }
    } else if (bx < GB + DB) {
        int n = (bx - GB) * 256 + threadIdx.x;
        if (n < N_NODES) dinv[n] = rsqrtf(1.0f + (float)cnt[n]);
    } else {
        int t = (bx - GB - DB) * 256 + threadIdx.x;   // NE*8 threads
        int e = t >> 3;
        int q = t & 7;
        int i = e / KNN;
        int j = j_idx[e];
        const int* jj = j_idx + j * KNN;
        int rt = 255;
        if (jj[q] == i) rt = q;
        if (jj[8 + q] == i) rt = min(rt, 8 + q);
        if (jj[16 + q] == i) rt = min(rt, 16 + q);
#pragma unroll
        for (int m = 1; m < 8; m <<= 1) rt = min(rt, __shfl_xor(rt, m));
        if (q == 0) revb[e] = (unsigned char)rt;
    }
}

// ---- Y = X @ W (layer 2), bf16 split-half output -------------------------
__global__ void k_gemm2(const unsigned short* __restrict__ X, const float* __restrict__ W,
                        unsigned short* __restrict__ Y0, unsigned short* __restrict__ Y1) {
    __shared__ float sW[64 * 64];
    __shared__ float sX[32 * 64];
    int row0 = blockIdx.x * 32;
    for (int t = threadIdx.x; t < 64 * 64; t += 256) sW[t] = W[t];
    for (int t = threadIdx.x; t < 32 * 64; t += 256) sX[t] = bf2f(X[row0 * 64 + t]);
    __syncthreads();
    int col = threadIdx.x & 63;
    int rl  = threadIdx.x >> 6;
    for (int r = rl; r < 32; r += 4) {
        float acc = 0.0f;
#pragma unroll
        for (int kk = 0; kk < 64; kk++) acc += sX[r * 64 + kk] * sW[kk * 64 + col];
        if (col < 32) Y0[(row0 + r) * 32 + col]      = f2bf(acc);
        else          Y1[(row0 + r) * 32 + col - 32] = f2bf(acc);
    }
}

// ---- CAP-overflow: zero targets then accumulate (single block; normally 0 work)
__global__ void k_ovfm(const unsigned short* __restrict__ X0, const unsigned short* __restrict__ X1,
                       float* __restrict__ ovfacc, const float* __restrict__ dinv,
                       const unsigned* __restrict__ ovf, const int* __restrict__ ovf_cnt) {
    int total = ovf_cnt[0] * 64;
    for (int t = threadIdx.x; t < total; t += 256)
        ovfacc[(ovf[t >> 6] & 0xffffu) * 64 + (t & 63)] = 0.0f;
    __syncthreads();
    for (int t = threadIdx.x; t < total; t += 256) {
        unsigned p = ovf[t >> 6];
        int f = t & 63;
        int c = (int)(p & 0xffffu), r = (int)(p >> 16);
        float x = (f < 32) ? bf2f(X0[r * 32 + f]) : bf2f(X1[r * 32 + f - 32]);
        atomicAdd(&ovfacc[c * 64 + f], dinv[r] * x);
    }
}

// ---- pull aggregation, one wave per TWO nodes, phased half-gathers -------
template<bool RELU, bool NORM>
__global__ void k_aggf2(const unsigned short* __restrict__ X0, const unsigned short* __restrict__ X1,
                        unsigned short* __restrict__ outF,     // full rows (layer 1)
                        unsigned short* __restrict__ O0,       // split (layer 2)
                        unsigned short* __restrict__ O1,
                        const float* __restrict__ ovfacc,
                        const float* __restrict__ dinv, const int* __restrict__ cnt,
                        const unsigned short* __restrict__ ebuf, const float* __restrict__ bias) {
    int w = (blockIdx.x * 256 + threadIdx.x) >> 6;   // wave id, 2 nodes/wave
    int lane = threadIdx.x & 63;
    int half = lane >> 5, sl = lane & 31;
    int n = w * 2 + half;
    if (n >= N_NODES) return;
    int deg = cnt[n];
    int bucketed = min(deg, CAP);
    int nb0 = min(bucketed, 32);
    int nb1 = bucketed - nb0;

    int   r0v = 0, r1v = 0;
    float d0v = 0.0f, d1v = 0.0f;
    if (sl < nb0) { r0v = (int)ebuf[n * CAP + sl];      d0v = dinv[r0v]; }
    if (sl < nb1) { r1v = (int)ebuf[n * CAP + 32 + sl]; d1v = dinv[r1v]; }

    float acc0 = 0.0f, acc1 = 0.0f;
    if (deg > CAP) {                     // overflow path (never in practice)
        acc0 = ovfacc[n * 64 + sl];
        acc1 = ovfacc[n * 64 + 32 + sl];
    }

    // Phase A: features 0..31 from X0 (2.56 MB, L2-resident)
    {
        int d = 0;
        for (; d + 3 < nb0; d += 4) {
            int   ra = __shfl(r0v, d, 32),     rb = __shfl(r0v, d + 1, 32);
            int   rc = __shfl(r0v, d + 2, 32), rd = __shfl(r0v, d + 3, 32);
            float ca = __shfl(d0v, d, 32),     cb = __shfl(d0v, d + 1, 32);
            float cc = __shfl(d0v, d + 2, 32), cd = __shfl(d0v, d + 3, 32);
            acc0 += ca * bf2f(X0[ra * 32 + sl]) + cb * bf2f(X0[rb * 32 + sl])
                  + cc * bf2f(X0[rc * 32 + sl]) + cd * bf2f(X0[rd * 32 + sl]);
        }
        for (; d < nb0; d++)
            acc0 += __shfl(d0v, d, 32) * bf2f(X0[__shfl(r0v, d, 32) * 32 + sl]);
        for (d = 0; d < nb1; d++)
            acc0 += __shfl(d1v, d, 32) * bf2f(X0[__shfl(r1v, d, 32) * 32 + sl]);
    }
    // Phase B: features 32..63 from X1
    {
        int d = 0;
        for (; d + 3 < nb0; d += 4) {
            int   ra = __shfl(r0v, d, 32),     rb = __shfl(r0v, d + 1, 32);
            int   rc = __shfl(r0v, d + 2, 32), rd = __shfl(r0v, d + 3, 32);
            float ca = __shfl(d0v, d, 32),     cb = __shfl(d0v, d + 1, 32);
            float cc = __shfl(d0v, d + 2, 32), cd = __shfl(d0v, d + 3, 32);
            acc1 += ca * bf2f(X1[ra * 32 + sl]) + cb * bf2f(X1[rb * 32 + sl])
                  + cc * bf2f(X1[rc * 32 + sl]) + cd * bf2f(X1[rd * 32 + sl]);
        }
        for (; d < nb0; d++)
            acc1 += __shfl(d0v, d, 32) * bf2f(X1[__shfl(r0v, d, 32) * 32 + sl]);
        for (d = 0; d < nb1; d++)
            acc1 += __shfl(d1v, d, 32) * bf2f(X1[__shfl(r1v, d, 32) * 32 + sl]);
    }

    float di = dinv[n];
    float v0 = di * acc0 + di * di * bf2f(X0[n * 32 + sl]) + bias[sl];
    float v1 = di * acc1 + di * di * bf2f(X1[n * 32 + sl]) + bias[32 + sl];
    if (RELU) { v0 = fmaxf(v0, 0.0f); v1 = fmaxf(v1, 0.0f); }
    if (NORM) {
        float s = v0 * v0 + v1 * v1;
#pragma unroll
        for (int m = 1; m < 32; m <<= 1) s += __shfl_xor(s, m, 32);
        float inv = 1.0f / fmaxf(sqrtf(s), 1e-12f);
        v0 *= inv; v1 *= inv;
        O0[n * 32 + sl] = f2bf(v0);
        O1[n * 32 + sl] = f2bf(v1);
    } else {
        outF[n * 64 + sl]      = f2bf(v0);
        outF[n * 64 + 32 + sl] = f2bf(v1);
    }
}

// ---- pass A: partial dot over feature half 0 (h0 = 2.56 MB, L2-resident) -
__global__ void k_dot0(const uint2* __restrict__ h0b, const int* __restrict__ j_idx,
                       float* __restrict__ pdot) {
    int t = blockIdx.x * 256 + threadIdx.x;   // NE*8 threads
    int e = t >> 3;
    int q = t & 7;
    int i = e / KNN;
    int j = j_idx[e];
    uint2 a = h0b[i * 8 + q];
    uint2 b = h0b[j * 8 + q];
    float s = bflo(a.x) * bflo(b.x) + bfhi(a.x) * bfhi(b.x)
            + bflo(a.y) * bflo(b.y) + bfhi(a.y) * bfhi(b.y);
    s += __shfl_xor(s, 1);
    s += __shfl_xor(s, 2);
    s += __shfl_xor(s, 4);
    if (q == 0) pdot[e] = s;
}

// ---- pass B: half 1 dot + finalize + symmetrize (NO atomics) -------------
__global__ void k_edgesym2(const uint2* __restrict__ h1b, const float* __restrict__ pdot,
                           const float* __restrict__ s_d, const int* __restrict__ j_idx,
                           const unsigned char* __restrict__ revb,
                           float* __restrict__ outS) {   // d_out + 2E, holds vals_s [2E]
    int t = blockIdx.x * 256 + threadIdx.x;   // NE*8 threads
    int e = t >> 3;
    int q = t & 7;
    int i = e / KNN;
    int j = j_idx[e];
    uint2 a = h1b[i * 8 + q];
    uint2 b = h1b[j * 8 + q];
    float s = bflo(a.x) * bflo(b.x) + bfhi(a.x) * bfhi(b.x)
            + bflo(a.y) * bflo(b.y) + bfhi(a.y) * bfhi(b.y);
    s += __shfl_xor(s, 1);
    s += __shfl_xor(s, 2);
    s += __shfl_xor(s, 4);
    if (q == 0) {
        s += pdot[e];
        float base = OMEGA * fmaxf(s, 0.0f);
        int rt = revb[e];
        float v, v2;
        if (rt != 255) {                     // reverse edge exists (rare)
            int rev = j * KNN + rt;
            v  = base + 0.5f * (1.0f - OMEGA) * (s_d[e] + s_d[rev]);
            v2 = 0.0f;
        } else {
            v  = base + (1.0f - OMEGA) * s_d[e];
            v2 = v;
        }
        outS[e] = v;
        outS[NE + e] = v2;
    }
}

// ---- binned in-edge degree accumulation: LDS per 512-node bucket ---------
// deg2in[n] = sum of v2 over learner edges with j_idx==n, no global atomics.
__global__ void k_jagg(const unsigned* __restrict__ jbbuf, const int* __restrict__ jbcnt,
                       const float* __restrict__ outSv2,   // = outS + NE
                       float* __restrict__ deg2in,
                       const unsigned* __restrict__ jovf, const int* __restrict__ jovf_cnt,
                       const int* __restrict__ j_idx, float* __restrict__ deg2ovf) {
    __shared__ float ld[512];
    int b = blockIdx.x;
    int tid = threadIdx.x;                   // 1024 threads
    if (b < NBUCK) {
        if (tid < 512) ld[tid] = 0.0f;
        __syncthreads();
        int n = min(jbcnt[b], JBCAP);
        for (int idx = tid; idx < n; idx += 1024) {
            unsigned p = jbbuf[b * JBCAP + idx];
            atomicAdd(&ld[p >> 20], outSv2[p & 0xFFFFFu]);
        }
        __syncthreads();
        if (tid < 512) {
            int node = b * 512 + tid;
            if (node < N_NODES) deg2in[node] = ld[tid];
        }
    } else {                                 // bin-overflow fallback (normally 0)
        int m = jovf_cnt[0];
        for (int t = (b - NBUCK) * 1024 + tid; t < m; t += 8 * 1024) {
            int e = (int)(jovf[t] & 0xFFFFFu);
            atomicAdd(&deg2ovf[j_idx[e]], outSv2[e]);
        }
    }
}

// ---- dinv2: out-edge segment sum (contiguous) + binned in-edge sums ------
__global__ void k_dinv2(const float* __restrict__ outS, const float* __restrict__ deg2in,
                        const float* __restrict__ deg2ovf, float* __restrict__ dinv2) {
    int n = blockIdx.x * 256 + threadIdx.x;
    if (n >= N_NODES) return;
    float d = deg2in[n] + deg2ovf[n];
    const float* p = outS + n * KNN;
#pragma unroll
    for (int q = 0; q < KNN; q++) d += p[q];
    dinv2[n] = (d > 0.0f) ? rsqrtf(fmaxf(d, 1e-12f)) : 0.0f;
}

// ---- final normalization: vals_norm = dinv2[r] * vals_s * dinv2[c] -------
__global__ void k_norm(const float* __restrict__ outS, const float* __restrict__ dinv2,
                       const int* __restrict__ j_idx, float* __restrict__ out) {
    int t = blockIdx.x * 256 + threadIdx.x;   // 2*NE threads
    int r, c;
    if (t < NE) { r = t / KNN; c = j_idx[t]; }
    else        { int e = t - NE; r = j_idx[e]; c = e / KNN; }
    out[t] = dinv2[r] * outS[t] * dinv2[c];
}

extern "C" void kernel_launch(void* const* d_in, const int* in_sizes, int n_in,
                              void* d_out, int out_size, void* d_ws, size_t ws_size,
                              hipStream_t stream) {
    const float* features = (const float*)d_in[0];
    const float* W1       = (const float*)d_in[1];
    const float* b1       = (const float*)d_in[2];
    const float* W2       = (const float*)d_in[3];
    const float* b2       = (const float*)d_in[4];
    const float* s_d      = (const float*)d_in[5];
    const int*   adj_row  = (const int*)d_in[6];
    const int*   adj_col  = (const int*)d_in[7];
    const int*   j_idx    = (const int*)d_in[9];
    float* out = (float*)d_out;

    const int N64 = N_NODES * 64;
    const int N32 = N_NODES * 32;
    // Workspace layout (zero region first):
    // [cnt N][deg2ovf N][ovfcnts 16][bcnt 80][jbcnt 80]  <- memset 0
    // [dinv N][dinv2 N][deg2in N][A0 N32 us][A1 N32 us][B16 N64 us][H0 N32 us][H1 N32 us]
    // [ebuf N*CAP us][OVFACC N64 f][ovf NE u][revb NE uc][bbuf][jbbuf][ovf2 NE u][jovf NE u]
    // pdot aliases bbuf (bbuf dead after k_scatter2; pdot born at k_dot0)
    int*   cnt     = (int*)d_ws;
    float* deg2ovf = (float*)(cnt + N_NODES);
    int*   ovfcnts = (int*)(deg2ovf + N_NODES);  // [0]=CAP ovf, [4]=adj bin ovf, [8]=learner bin ovf
    int*   bcnt    = ovfcnts + 16;
    int*   jbcnt   = bcnt + NBUCK;
    float* dinv    = (float*)(jbcnt + NBUCK);
    float* dinv2   = dinv + N_NODES;
    float* deg2in  = dinv2 + N_NODES;
    unsigned short* A0  = (unsigned short*)(deg2in + N_NODES);
    unsigned short* A1  = A0 + N32;
    unsigned short* B16 = A1 + N32;
    unsigned short* H0  = B16 + N64;
    unsigned short* H1  = H0 + N32;
    unsigned short* ebuf = H1 + N32;             // N*CAP ushorts
    float*    OVFACC = (float*)(ebuf + N_NODES * CAP);
    unsigned* ovf    = (unsigned*)(OVFACC + N64);
    unsigned char* revb = (unsigned char*)(ovf + NE);
    unsigned* bbuf   = (unsigned*)(revb + NE);   // NBUCK*BCAP
    unsigned* jbbuf  = bbuf + NBUCK * BCAP;      // NBUCK*JBCAP
    unsigned* ovf2   = jbbuf + NBUCK * JBCAP;    // NE
    unsigned* jovf   = ovf2 + NE;                // NE
    float*    pdot   = (float*)bbuf;             // alias

    // Re-init (ws is poisoned 0xAA before every call)
    size_t zero_bytes = (size_t)(2 * N_NODES + 16 + 2 * NBUCK) * 4;
    hipMemsetAsync(cnt, 0, zero_bytes, stream);

    // Bin both edge sets, then XCD-affine scatter (adj) -> ebuf + cnt
    const int NB_ADJ = (NE + 256 * EPT - 1) / (256 * EPT);
    k_bin<<<2 * NB_ADJ, 256, 0, stream>>>(adj_row, adj_col, j_idx,
                                          bcnt, bbuf, ovf2, ovfcnts + 4,
                                          jbcnt, jbbuf, jovf, ovfcnts + 8);
    k_scatter2<<<8 * LBUCK * (BCAP / PBCH) + 8, 256, 0, stream>>>(bbuf, bcnt, cnt, ebuf,
                                                                  ovf, ovfcnts, ovf2, ovfcnts + 4);

    // Fused: gemm layer1 + dinv + reverse-edge scan
    const int GB = N_NODES / 32, DB = (N_NODES + 255) / 256, RB = NE * 8 / 256;
    k_fused1<<<GB + DB + RB, 256, 0, stream>>>(features, W1, A0, A1, cnt, dinv, j_idx, revb);

    // Layer 1 aggregate
    k_ovfm<<<1, 256, 0, stream>>>(A0, A1, OVFACC, dinv, ovf, ovfcnts);
    k_aggf2<true, false><<<(N_NODES / 2 * 64 + 255) / 256, 256, 0, stream>>>(
        A0, A1, B16, nullptr, nullptr, OVFACC, dinv, cnt, ebuf, b1);

    // Layer 2
    k_gemm2<<<N_NODES / 32, 256, 0, stream>>>(B16, W2, A0, A1);
    k_ovfm<<<1, 256, 0, stream>>>(A0, A1, OVFACC, dinv, ovf, ovfcnts);
    k_aggf2<false, true><<<(N_NODES / 2 * 64 + 255) / 256, 256, 0, stream>>>(
        A0, A1, nullptr, H0, H1, OVFACC, dinv, cnt, ebuf, b2);

    // Edge scores: half-0 partial dots, then half-1 + symmetrize (atomic-free)
    float* outS = out + 2 * NE;
    k_dot0<<<NE * 8 / 256, 256, 0, stream>>>((const uint2*)H0, j_idx, pdot);
    k_edgesym2<<<NE * 8 / 256, 256, 0, stream>>>((const uint2*)H1, pdot, s_d, j_idx, revb, outS);

    // Binned in-edge degree accumulation, then dinv2, then final normalize
    k_jagg<<<NBUCK + 8, 1024, 0, stream>>>(jbbuf, jbcnt, outS + NE, deg2in,
                                           jovf, ovfcnts + 8, j_idx, deg2ovf);
    k_dinv2<<<(N_NODES + 255) / 256, 256, 0, stream>>>(outS, deg2in, deg2ovf, dinv2);
    k_norm<<<2 * NE / 256, 256, 0, stream>>>(outS, dinv2, j_idx, out);
}